// Round 3
// baseline (18840.656 us; speedup 1.0000x reference)
//
#include <hip/hip_runtime.h>
#include <math.h>

#define H 4096
#define E 64
#define T_TOTAL 32768
#define TB 64               // tokens per block
#define HK 128              // K-chunk in floats
#define NCHUNK (H / HK)     // 32
#define NSTEP (HK / 4)      // 32 float4-steps per chunk
#define NT 512              // 8 waves

// d_out layout (floats):
//   logits : [0, 2097152)       = [4,8192,64]
//   weights: [2097152, 2162688) = [32768,2]
//   indices: [2162688, 2228224) = [32768,2] (written as float values)
#define OFF_W 2097152
#define OFF_I 2162688

__global__ __launch_bounds__(NT, 4)   // cap VGPR at 128 -> 2 blocks/CU with 64KB LDS
void moe_router_kernel(const float* __restrict__ x,
                       const float* __restrict__ W,
                       float* __restrict__ out)
{
    // Double-buffered W chunk, XOR-swizzled: row e, logical col4 c stored at
    // col4 (c ^ (e&31)). Read (fixed c, all 64 rows) then spreads evenly
    // across all 8 16B bank-groups -> at the b128 floor.
    __shared__ float ws[2][E * HK];   // 2 x 32 KB

    const int tid  = threadIdx.x;
    const int wid  = tid >> 6;        // wave 0..7 -> token group
    const int lane = tid & 63;        // lane = expert index
    const int tok0 = blockIdx.x * TB;

    // --- x row pointers: 8 tokens owned by this wave (wave-uniform addrs,
    //     lanes broadcast). Advanced by HK each chunk so in-loop offsets are
    //     compile-time immediates.
    const float* xc[8];
#pragma unroll
    for (int i = 0; i < 8; ++i)
        xc[i] = x + (size_t)(tok0 + wid * 8 + i) * H;

    // --- W staging mapping (coalesced global reads):
    //     thread covers row se = wid*8 + (lane>>3), col4s sc+8j (j=0..3)
    const int se = wid * 8 + (lane >> 3);
    const int sc = lane & 7;
    const float* wsrc = W + (size_t)se * H + (sc << 2);
    int wdst[4];
#pragma unroll
    for (int j = 0; j < 4; ++j)
        wdst[j] = se * HK + (((sc + 8 * j) ^ (se & 31)) << 2);

    // LDS read base: row = lane (expert), col4 = s ^ (lane&31)
    const int rbase = lane * HK;
    const int rswz  = lane & 31;

    // --- prologue: stage W chunk 0 into ws[0] ---
    {
        float4 w0[4];
#pragma unroll
        for (int j = 0; j < 4; ++j)
            w0[j] = *(const float4*)(wsrc + j * 32);
#pragma unroll
        for (int j = 0; j < 4; ++j)
            *(float4*)&ws[0][wdst[j]] = w0[j];
    }

    // --- prime x ring: global steps 0,1 (slots 0,1) ---
    float4 ring0[8], ring1[8];
#pragma unroll
    for (int i = 0; i < 8; ++i) ring0[i] = *(const float4*)(xc[i] + 0);
#pragma unroll
    for (int i = 0; i < 8; ++i) ring1[i] = *(const float4*)(xc[i] + 4);

    float acc[8];
#pragma unroll
    for (int i = 0; i < 8; ++i) acc[i] = 0.f;

    __syncthreads();

    for (int kc = 0; kc < NCHUNK; ++kc) {
        const float* wp = ws[kc & 1];
        const bool pf = (kc < NCHUNK - 1);

        // T14 issue-early: load next W chunk into regs, write to LDS after compute
        float4 wreg[4];
        if (pf) {
            const float* wsn = wsrc + (size_t)(kc + 1) * HK;
#pragma unroll
            for (int j = 0; j < 4; ++j)
                wreg[j] = *(const float4*)(wsn + j * 32);
        }

#pragma unroll
        for (int s = 0; s < NSTEP; ++s) {
            const float4 wv = *(const float4*)&wp[rbase + ((s ^ rswz) << 2)];
            if ((s & 1) == 0) {
#pragma unroll
                for (int i = 0; i < 8; ++i) {
                    acc[i] = fmaf(ring0[i].x, wv.x, acc[i]);
                    acc[i] = fmaf(ring0[i].y, wv.y, acc[i]);
                    acc[i] = fmaf(ring0[i].z, wv.z, acc[i]);
                    acc[i] = fmaf(ring0[i].w, wv.w, acc[i]);
                }
                if (kc < NCHUNK - 1 || s < NSTEP - 2) {
                    // refill slot 0 with step s+2 (offset is compile-time imm)
#pragma unroll
                    for (int i = 0; i < 8; ++i)
                        ring0[i] = *(const float4*)(xc[i] + (s + 2) * 4);
                }
            } else {
#pragma unroll
                for (int i = 0; i < 8; ++i) {
                    acc[i] = fmaf(ring1[i].x, wv.x, acc[i]);
                    acc[i] = fmaf(ring1[i].y, wv.y, acc[i]);
                    acc[i] = fmaf(ring1[i].z, wv.z, acc[i]);
                    acc[i] = fmaf(ring1[i].w, wv.w, acc[i]);
                }
                if (kc < NCHUNK - 1 || s < NSTEP - 2) {
#pragma unroll
                    for (int i = 0; i < 8; ++i)
                        ring1[i] = *(const float4*)(xc[i] + (s + 2) * 4);
                }
            }
        }

        // advance x pointers to next chunk
#pragma unroll
        for (int i = 0; i < 8; ++i) xc[i] += HK;

        // write prefetched W into the other buffer (swizzled), then barrier
        if (pf) {
            float* wn = ws[(kc & 1) ^ 1];
#pragma unroll
            for (int j = 0; j < 4; ++j)
                *(float4*)&wn[wdst[j]] = wreg[j];
        }
        __syncthreads();
    }

    // ---- epilogue: logits out (coalesced) + LDS tile for top-2 ----
    float* lt = (float*)ws;            // 64 x 65 tile (16.6 KB)
#pragma unroll
    for (int i = 0; i < 8; ++i) {
        const int t = wid * 8 + i;
        lt[t * 65 + lane] = acc[i];
        out[(size_t)(tok0 + t) * E + lane] = acc[i];
    }
    __syncthreads();

    if (tid < TB) {
        const float* row = lt + tid * 65;
        float v1 = -INFINITY, v2 = -INFINITY;
        int i1 = 0, i2 = 0;
        for (int e = 0; e < E; ++e) {
            float v = row[e];
            if (v > v1)      { v2 = v1; i2 = i1; v1 = v; i1 = e; }
            else if (v > v2) { v2 = v;  i2 = e; }
        }
        // softmax->top2->renorm == sigmoid of logit gap (Z cancels)
        float ee = expf(v2 - v1);
        float w1 = 1.0f / (1.0f + ee);
        float w2 = ee * w1;

        const size_t tok = (size_t)tok0 + tid;
        out[OFF_W + tok * 2]     = w1;
        out[OFF_W + tok * 2 + 1] = w2;
        out[OFF_I + tok * 2]     = (float)i1;
        out[OFF_I + tok * 2 + 1] = (float)i2;
    }
}

extern "C" void kernel_launch(void* const* d_in, const int* in_sizes, int n_in,
                              void* d_out, int out_size, void* d_ws, size_t ws_size,
                              hipStream_t stream) {
    const float* x = (const float*)d_in[0];
    const float* W = (const float*)d_in[1];
    float* out = (float*)d_out;

    dim3 grid(T_TOTAL / TB);   // 512 blocks = 2/CU
    dim3 block(NT);
    moe_router_kernel<<<grid, block, 0, stream>>>(x, W, out);
}

// Round 5
// 768.186 us; speedup vs baseline: 24.5262x; 24.5262x over previous
//
#include <hip/hip_runtime.h>
#include <math.h>

#define H 4096
#define E 64
#define T_TOTAL 32768
#define TB 64             // tokens per block (= lanes)
#define NT 512            // 8 waves = 8 expert groups
#define NEPT 8            // experts per thread

// d_out layout (floats):
//   logits : [0, 2097152)       = [4,8192,64]
//   weights: [2097152, 2162688) = [32768,2]
//   indices: [2162688, 2228224) = [32768,2] (as float values)
#define OFF_W 2097152
#define OFF_I 2162688

// One 16-K sub-phase: 8 experts x 4 K, W via wave-uniform loads (SGPR path),
// accumulation order per (token,expert) is EXACTLY ascending K — bit-identical
// to the verified R1 kernel (tie-safety on the fixed dataset).
#define SUB(xv, kk)                                                        \
    do {                                                                   \
        _Pragma("unroll")                                                  \
        for (int e = 0; e < NEPT; ++e) {                                   \
            const float4 wv = *(const float4*)(w0 + (size_t)e * H + (kk)); \
            acc[e] = fmaf((xv).x, wv.x, acc[e]);                           \
            acc[e] = fmaf((xv).y, wv.y, acc[e]);                           \
            acc[e] = fmaf((xv).z, wv.z, acc[e]);                           \
            acc[e] = fmaf((xv).w, wv.w, acc[e]);                           \
        }                                                                  \
    } while (0)

__global__ __launch_bounds__(NT, 4)   // VGPR cap 128; ~70 expected -> no spill
void moe_router_kernel(const float* __restrict__ x,
                       const float* __restrict__ W,
                       float* __restrict__ out)
{
    __shared__ float lt[TB * 65];     // logits exchange tile (epilogue only)

    const int tid  = threadIdx.x;
    const int lane = tid & 63;                                   // token
    const int wid  = __builtin_amdgcn_readfirstlane(tid >> 6);   // expert group
    const int e0   = wid * NEPT;
    const int tok0 = blockIdx.x * TB;
    const int t    = tok0 + lane;

    const float* xr = x + (size_t)t * H;          // per-lane token row
    const float* w0 = W + (size_t)e0 * H;         // wave-uniform expert rows

    float acc[NEPT];
#pragma unroll
    for (int e = 0; e < NEPT; ++e) acc[e] = 0.f;

    // x pipeline: two 16-K phases in registers (8 float4 = 32 VGPR)
    float4 xa[4], xb[4];
#pragma unroll
    for (int j = 0; j < 4; ++j) xa[j] = *(const float4*)(xr + j * 4);
#pragma unroll
    for (int j = 0; j < 4; ++j) xb[j] = *(const float4*)(xr + 16 + j * 4);

    for (int it = 0; it < H / 32; ++it) {         // 128 iterations, 32 K each
        const int kA = it * 32;

        // phase A: compute K [kA, kA+16)
        SUB(xa[0], kA);
        SUB(xa[1], kA + 4);
        SUB(xa[2], kA + 8);
        SUB(xa[3], kA + 12);
        if (it < H / 32 - 1) {                    // refill xa for next body
#pragma unroll
            for (int j = 0; j < 4; ++j)
                xa[j] = *(const float4*)(xr + kA + 32 + j * 4);
        }

        // phase B: compute K [kA+16, kA+32)
        SUB(xb[0], kA + 16);
        SUB(xb[1], kA + 20);
        SUB(xb[2], kA + 24);
        SUB(xb[3], kA + 28);
        if (it < H / 32 - 1) {                    // refill xb for next body
#pragma unroll
            for (int j = 0; j < 4; ++j)
                xb[j] = *(const float4*)(xr + kA + 48 + j * 4);
        }
    }

    // ---- logits out (from registers, bit-identical chain) ----
    float* orow = out + (size_t)t * E + e0;
    {
        float4 v0; v0.x = acc[0]; v0.y = acc[1]; v0.z = acc[2]; v0.w = acc[3];
        float4 v1; v1.x = acc[4]; v1.y = acc[5]; v1.z = acc[6]; v1.w = acc[7];
        *(float4*)(orow)     = v0;
        *(float4*)(orow + 4) = v1;
    }

    // ---- exchange for top-2 (stride 65 -> conflict-free-ish, epilogue-only) ----
#pragma unroll
    for (int e = 0; e < NEPT; ++e)
        lt[lane * 65 + e0 + e] = acc[e];
    __syncthreads();

    if (tid < TB) {
        const float* row = lt + tid * 65;
        float v1 = -INFINITY, v2 = -INFINITY;
        int i1 = 0, i2 = 0;
        for (int e = 0; e < E; ++e) {
            float v = row[e];
            if (v > v1)      { v2 = v1; i2 = i1; v1 = v; i1 = e; }
            else if (v > v2) { v2 = v;  i2 = e; }
        }
        // softmax -> top2 -> renorm == sigmoid of logit gap (Z cancels)
        float ee = expf(v2 - v1);
        float w1 = 1.0f / (1.0f + ee);
        float w2 = ee * w1;

        const size_t tok = (size_t)tok0 + tid;
        out[OFF_W + tok * 2]     = w1;
        out[OFF_W + tok * 2 + 1] = w2;
        out[OFF_I + tok * 2]     = (float)i1;
        out[OFF_I + tok * 2 + 1] = (float)i2;
    }
}

extern "C" void kernel_launch(void* const* d_in, const int* in_sizes, int n_in,
                              void* d_out, int out_size, void* d_ws, size_t ws_size,
                              hipStream_t stream) {
    const float* x = (const float*)d_in[0];
    const float* W = (const float*)d_in[1];
    float* out = (float*)d_out;

    dim3 grid(T_TOTAL / TB);   // 512 blocks -> 2 blocks/CU, 4 waves/SIMD
    dim3 block(NT);
    moe_router_kernel<<<grid, block, 0, stream>>>(x, W, out);
}

// Round 6
// 557.838 us; speedup vs baseline: 33.7744x; 1.3771x over previous
//
#include <hip/hip_runtime.h>
#include <math.h>

#define H 4096
#define E 64
#define T_TOTAL 32768
#define TB 64             // tokens per block (= lanes)
#define NT 512            // 8 waves = 8 expert groups
#define NEPT 8            // experts per thread
#define KC 64             // K per chunk
#define NCH (H / KC)      // 64 chunks

// d_out layout (floats):
//   logits : [0, 2097152)       = [4,8192,64]
//   weights: [2097152, 2162688) = [32768,2]
//   indices: [2162688, 2228224) = [32768,2] (as float values)
#define OFF_W 2097152
#define OFF_I 2162688

// Per chunk: compute 16 K4-substeps (ascending K -> bit-identical chain to the
// verified R1/R5 kernels), W from LDS broadcast reads, x from per-lane register
// double-buffer (xa = first 32K of chunk, xb = second 32K, refilled 8 substeps
// ahead of use). PREF is a compile-time 0/1: stages next W chunk (T14 split:
// load early, ds_write late) and prefetches next chunk's xa.
#define CHUNK_BODY(PREF)                                                      \
  do {                                                                        \
    float4 wreg0, wreg1;                                                      \
    if (PREF) { wreg0 = *(const float4*)wsrc0; wreg1 = *(const float4*)wsrc1; } \
    const float* wrow = &wbuf[buf][0][0] + e0 * KC;                           \
    _Pragma("unroll")                                                         \
    for (int s = 0; s < 8; ++s) {                                             \
      _Pragma("unroll")                                                       \
      for (int e = 0; e < NEPT; ++e) {                                        \
        const float4 wv = *(const float4*)(wrow + e * KC + s * 4);            \
        acc[e] = fmaf(xa[s].x, wv.x, acc[e]);                                 \
        acc[e] = fmaf(xa[s].y, wv.y, acc[e]);                                 \
        acc[e] = fmaf(xa[s].z, wv.z, acc[e]);                                 \
        acc[e] = fmaf(xa[s].w, wv.w, acc[e]);                                 \
      }                                                                       \
      xb[s] = *(const float4*)(xp + 32 + 4 * s);                              \
    }                                                                         \
    _Pragma("unroll")                                                         \
    for (int s = 0; s < 8; ++s) {                                             \
      _Pragma("unroll")                                                       \
      for (int e = 0; e < NEPT; ++e) {                                        \
        const float4 wv = *(const float4*)(wrow + e * KC + 32 + s * 4);       \
        acc[e] = fmaf(xb[s].x, wv.x, acc[e]);                                 \
        acc[e] = fmaf(xb[s].y, wv.y, acc[e]);                                 \
        acc[e] = fmaf(xb[s].z, wv.z, acc[e]);                                 \
        acc[e] = fmaf(xb[s].w, wv.w, acc[e]);                                 \
      }                                                                       \
      if (PREF) xa[s] = *(const float4*)(xp + 64 + 4 * s);                    \
    }                                                                         \
    if (PREF) {                                                               \
      float* wd = &wbuf[buf ^ 1][0][0] + tid * 4;                             \
      *(float4*)wd = wreg0;                                                   \
      *(float4*)(wd + 2048) = wreg1;                                          \
      wsrc0 += KC; wsrc1 += KC;                                               \
    }                                                                         \
    xp += KC;                                                                 \
    __syncthreads();                                                          \
    buf ^= 1;                                                                 \
  } while (0)

__global__ __launch_bounds__(NT, 4)   // 16 waves/CU -> VGPR cap 128
void moe_router_kernel(const float* __restrict__ x,
                       const float* __restrict__ W,
                       float* __restrict__ out)
{
    __shared__ float wbuf[2][E][KC];   // double-buffered W chunk, 2 x 16 KB

    const int tid  = threadIdx.x;
    const int lane = tid & 63;         // token
    const int wid  = tid >> 6;         // expert group
    const int e0   = wid * NEPT;
    const int tok0 = blockIdx.x * TB;
    const int t    = tok0 + lane;

    const float* xp = x + (size_t)t * H;                   // per-lane token row
    // W staging: flat float4-unit u of the [64][KC] chunk; thread covers
    // u = tid and u = tid + 512. src(u) = W + (u>>4)*H + k0 + (u&15)*4.
    const float* wsrc0 = W + (size_t)(tid >> 4) * H + (tid & 15) * 4;
    const float* wsrc1 = wsrc0 + (size_t)32 * H;           // (tid+512)>>4 = +32

    float acc[NEPT];
#pragma unroll
    for (int e = 0; e < NEPT; ++e) acc[e] = 0.f;

    // ---- prologue: stage W chunk 0, prime xa with K [0,32) ----
    {
        float4 w0 = *(const float4*)wsrc0;
        float4 w1 = *(const float4*)wsrc1;
        float* wd = &wbuf[0][0][0] + tid * 4;
        *(float4*)wd = w0;
        *(float4*)(wd + 2048) = w1;
        wsrc0 += KC; wsrc1 += KC;
    }
    float4 xa[8], xb[8];
#pragma unroll
    for (int s = 0; s < 8; ++s) xa[s] = *(const float4*)(xp + 4 * s);
    __syncthreads();

    int buf = 0;
    for (int c = 0; c < NCH - 1; ++c) CHUNK_BODY(1);
    CHUNK_BODY(0);

    // ---- logits out (from registers, bit-identical chain) ----
    float* orow = out + (size_t)t * E + e0;
    {
        float4 v0; v0.x = acc[0]; v0.y = acc[1]; v0.z = acc[2]; v0.w = acc[3];
        float4 v1; v1.x = acc[4]; v1.y = acc[5]; v1.z = acc[6]; v1.w = acc[7];
        *(float4*)(orow)     = v0;
        *(float4*)(orow + 4) = v1;
    }

    // ---- exchange for top-2 (reuse wbuf; stride 65 -> 2-way = free) ----
    float* lt = &wbuf[0][0][0];        // 64 x 65 tile (16.6 KB of the 32 KB)
#pragma unroll
    for (int e = 0; e < NEPT; ++e)
        lt[lane * 65 + e0 + e] = acc[e];
    __syncthreads();

    if (tid < TB) {
        const float* row = lt + tid * 65;
        float v1 = -INFINITY, v2 = -INFINITY;
        int i1 = 0, i2 = 0;
        for (int e = 0; e < E; ++e) {
            float v = row[e];
            if (v > v1)      { v2 = v1; i2 = i1; v1 = v; i1 = e; }
            else if (v > v2) { v2 = v;  i2 = e; }
        }
        // softmax -> top2 -> renorm == sigmoid of logit gap (Z cancels)
        float ee = expf(v2 - v1);
        float w1 = 1.0f / (1.0f + ee);
        float w2 = ee * w1;

        const size_t tok = (size_t)tok0 + tid;
        out[OFF_W + tok * 2]     = w1;
        out[OFF_W + tok * 2 + 1] = w2;
        out[OFF_I + tok * 2]     = (float)i1;
        out[OFF_I + tok * 2 + 1] = (float)i2;
    }
}

extern "C" void kernel_launch(void* const* d_in, const int* in_sizes, int n_in,
                              void* d_out, int out_size, void* d_ws, size_t ws_size,
                              hipStream_t stream) {
    const float* x = (const float*)d_in[0];
    const float* W = (const float*)d_in[1];
    float* out = (float*)d_out;

    dim3 grid(T_TOTAL / TB);   // 512 blocks -> 2 blocks/CU, 4 waves/SIMD
    dim3 block(NT);
    moe_router_kernel<<<grid, block, 0, stream>>>(x, W, out);
}